// Round 8
// baseline (135.123 us; speedup 1.0000x reference)
//
#include <hip/hip_runtime.h>
#include <math.h>

#define N_NODES 4096
#define F_IN    512
#define F_OUT   64
#define ALPHA   0.2f
#define NPART   16

typedef _Float16 half8 __attribute__((ext_vector_type(8)));
typedef _Float16 half4 __attribute__((ext_vector_type(4)));
typedef float    floatx4 __attribute__((ext_vector_type(4)));

union H8U4 { half8 h; uint32_t u[4]; };

// ---------------- k_pre: FUSED bitmap-pack + hW (R7-verified, verbatim) ----------------
__global__ __launch_bounds__(512) void k_pre(const float* __restrict__ x,
                                             const int* __restrict__ adj,
                                             const float* __restrict__ W,
                                             const float* __restrict__ a,
                                             uint32_t* __restrict__ bm,
                                             float* __restrict__ h,
                                             _Float16* __restrict__ hT,
                                             float* __restrict__ e1) {
    __shared__ float red[8][16][64];   // used by hW blocks only (32 KB)
    int gb  = blockIdx.x;
    int tid = threadIdx.x;

    if (gb < 1024) {   // ---- bitmap pack ----
        int wid = gb * 512 + tid;                  // 524288 words total
        const int* p = adj + (size_t)wid * 32;
        uint32_t m = 0;
#pragma unroll
        for (int q = 0; q < 8; ++q) {
            int4 v = *(const int4*)(p + q * 4);
            m |= (v.x > 0 ? 1u : 0u) << (q * 4 + 0);
            m |= (v.y > 0 ? 1u : 0u) << (q * 4 + 1);
            m |= (v.z > 0 ? 1u : 0u) << (q * 4 + 2);
            m |= (v.w > 0 ? 1u : 0u) << (q * 4 + 3);
        }
        bm[wid] = m;
        return;
    }

    // ---- hW part (W-gather, R3/R5-verified) ----
    int lane = tid & 63;
    int w    = tid >> 6;               // 0..7
    int i0   = (gb - 1024) * 16;
    int n    = lane & 15;
    int quad = lane >> 4;

    floatx4 acc[4] = {{0,0,0,0},{0,0,0,0},{0,0,0,0},{0,0,0,0}};

    const float* xr = x + (size_t)(i0 + n) * F_IN + w * 64 + quad * 8;
#pragma unroll
    for (int kk = 0; kk < 64; kk += 32) {
        float4 x0 = *(const float4*)(xr + kk);
        float4 x1 = *(const float4*)(xr + kk + 4);
        half8 af = {(_Float16)x0.x, (_Float16)x0.y, (_Float16)x0.z, (_Float16)x0.w,
                    (_Float16)x1.x, (_Float16)x1.y, (_Float16)x1.z, (_Float16)x1.w};
        int k0 = w * 64 + kk + quad * 8;
#pragma unroll
        for (int g = 0; g < 4; ++g) {
            const float* wc = W + (size_t)k0 * F_OUT + g * 16 + n;   // column t = g*16+n
            half8 bf = {(_Float16)wc[0 * 64], (_Float16)wc[1 * 64], (_Float16)wc[2 * 64], (_Float16)wc[3 * 64],
                        (_Float16)wc[4 * 64], (_Float16)wc[5 * 64], (_Float16)wc[6 * 64], (_Float16)wc[7 * 64]};
            acc[g] = __builtin_amdgcn_mfma_f32_16x16x32_f16(af, bf, acc[g], 0, 0, 0);
        }
    }
#pragma unroll
    for (int g = 0; g < 4; ++g)
#pragma unroll
        for (int r = 0; r < 4; ++r)
            red[w][g * 4 + r][lane] = acc[g][r];
    __syncthreads();
    if (w != 0) return;
#pragma unroll
    for (int g = 0; g < 4; ++g)
#pragma unroll
        for (int r = 0; r < 4; ++r) {
            float v = 0.f;
#pragma unroll
            for (int ww = 0; ww < 8; ++ww)
                v += red[ww][g * 4 + r][lane];
            acc[g][r] = v;
        }
#pragma unroll
    for (int g = 0; g < 4; ++g) {
        half4 hv;
#pragma unroll
        for (int r = 0; r < 4; ++r) {
            h[(size_t)(i0 + quad * 4 + r) * F_OUT + g * 16 + n] = acc[g][r];
            hv[r] = (_Float16)acc[g][r];
        }
        *(half4*)(hT + (size_t)(g * 16 + n) * N_NODES + i0 + quad * 4) = hv;
    }
    float a1v[4];
#pragma unroll
    for (int g = 0; g < 4; ++g) a1v[g] = a[g * 16 + n];
#pragma unroll
    for (int r = 0; r < 4; ++r) {
        float v = acc[0][r] * a1v[0] + acc[1][r] * a1v[1] + acc[2][r] * a1v[2] + acc[3][r] * a1v[3];
        v += __shfl_xor(v, 1, 64);
        v += __shfl_xor(v, 2, 64);
        v += __shfl_xor(v, 4, 64);
        v += __shfl_xor(v, 8, 64);
        if (n == 0) e1[i0 + quad * 4 + r] = v;
    }
}

// ---------------- k_main3: ZERO-STAGING masked MFMA (B direct from L2, no main-loop barriers) ----------------
// grid 1024: b -> rb = b>>4 (64-row group), s = b&15 (256-col superchunk = 8 x 32-col chunks).
// Inputs are L2-resident (bm 2 MB, hT 512 KB) -> no LDS staging, no DMA, no barriers after the
// prologue. LDS = 1.8 KB -> 4 blocks/CU. Masked-P values and summation order bit-identical to R0.
__global__ __launch_bounds__(256, 4) void k_main3(const uint32_t* __restrict__ bm,
                                                  const float* __restrict__ h,
                                                  const float* __restrict__ e1,
                                                  const float* __restrict__ a,
                                                  const _Float16* __restrict__ hT,
                                                  float* __restrict__ out_part,
                                                  float* __restrict__ den_part) {
    __shared__ _Float16 lds_P[256];           //  0.5 KB
    __shared__ float    lds_part[4][64];      //  1 KB
    __shared__ float    TqS[64];              //  0.25 KB

    int tid  = threadIdx.x;
    int lane = tid & 63;
    int w    = tid >> 6;               // 0..3
    int b    = blockIdx.x;
    int rb   = b >> 4;                 // 64-row group (0..63)
    int s    = b & 15;                 // 256-col superchunk (0..15)
    int i0   = rb * 64 + w * 16;
    int n    = lane & 15;
    int quad = lane >> 4;

    // ---- pre-load bitmap row-slice: row i0+n, cols s*256..+255 = 8 words (L2-resident) ----
    const uint32_t* bmr = bm + (size_t)(i0 + n) * (N_NODES / 32) + s * 8;
    uint4 bwa = *(const uint4*)(bmr + 0);
    uint4 bwb = *(const uint4*)(bmr + 4);
    uint32_t bw[8] = {bwa.x, bwa.y, bwa.z, bwa.w, bwb.x, bwb.y, bwb.z, bwb.w};

    // ---- prologue: Tq[rb][t] = sum_r a2[r] * h[(r*64+rb)*64 + t]  (R0-verified) ----
    {
        int t  = tid & 63;
        int rp = tid >> 6;
        const float* a2 = a + F_OUT;
        float ssum = 0.f;
#pragma unroll
        for (int rr = 0; rr < 16; ++rr) {
            int r = rp * 16 + rr;
            ssum += a2[r] * h[(size_t)r * 4096 + rb * 64 + t];
        }
        lds_part[rp][t] = ssum;
    }
    __syncthreads();
    if (tid < 64)
        TqS[tid] = lds_part[0][tid] + lds_part[1][tid] + lds_part[2][tid] + lds_part[3][tid];
    __syncthreads();
    // ---- P strip for this block's 256 cols: 1 expf per thread ----
    {
        int j = s * 256 + tid;
        float e0 = e1[j] + TqS[tid & 63];
        e0 = e0 > 0.f ? e0 : ALPHA * e0;
        lds_P[tid] = (_Float16)__expf(e0);
    }
    __syncthreads();   // the LAST barrier in the kernel

    floatx4 acc[4] = {{0,0,0,0},{0,0,0,0},{0,0,0,0},{0,0,0,0}};
    floatx4 accd = {0, 0, 0, 0};
    _Float16 one_h = (n == 0) ? (_Float16)1.0f : (_Float16)0.0f;
    half8 ones_f = {one_h, one_h, one_h, one_h, one_h, one_h, one_h, one_h};

    const int jb = s * 256;
    // ---- 8 chunks x 32 cols: mask from registers, P from LDS, B straight from L2 ----
#pragma unroll
    for (int c = 0; c < 8; ++c) {
        uint32_t mbyte = bw[c] >> (quad * 8);   // bits for cols jb + c*32 + quad*8 .. +7, row i0+n
        H8U4 pv, af;
        pv.h = *(const half8*)&lds_P[c * 32 + quad * 8];
        af.u[0] = pv.u[0] & (((mbyte &   1u) ? 0x0000FFFFu : 0u) | ((mbyte &   2u) ? 0xFFFF0000u : 0u));
        af.u[1] = pv.u[1] & (((mbyte &   4u) ? 0x0000FFFFu : 0u) | ((mbyte &   8u) ? 0xFFFF0000u : 0u));
        af.u[2] = pv.u[2] & (((mbyte &  16u) ? 0x0000FFFFu : 0u) | ((mbyte &  32u) ? 0xFFFF0000u : 0u));
        af.u[3] = pv.u[3] & (((mbyte &  64u) ? 0x0000FFFFu : 0u) | ((mbyte & 128u) ? 0xFFFF0000u : 0u));
#pragma unroll
        for (int g4 = 0; g4 < 4; ++g4) {
            // identical bits to the old LDS path: hT[g4*16+n][jb + c*32 + quad*8 .. +7]
            half8 bf = *(const half8*)(hT + (size_t)(g4 * 16 + n) * N_NODES + jb + c * 32 + quad * 8);
            acc[g4] = __builtin_amdgcn_mfma_f32_16x16x32_f16(af.h, bf, acc[g4], 0, 0, 0);
        }
        accd = __builtin_amdgcn_mfma_f32_16x16x32_f16(af.h, ones_f, accd, 0, 0, 0);
    }

    // ---- store this superchunk's private partial (C: row = quad*4+r, col = g4*16+n) ----
    float* op = out_part + ((size_t)s * N_NODES + i0) * F_OUT;
#pragma unroll
    for (int g4 = 0; g4 < 4; ++g4)
#pragma unroll
        for (int r = 0; r < 4; ++r)
            op[(quad * 4 + r) * F_OUT + g4 * 16 + n] = acc[g4][r];
    if (n == 0) {
#pragma unroll
        for (int r = 0; r < 4; ++r)
            den_part[s * N_NODES + i0 + quad * 4 + r] = accd[r];
    }
}

// ---------------- k_out: out = relu(sum_s out_part / sum_s den_part) + bias (float4) ----------------
__global__ __launch_bounds__(128) void k_out(const float* __restrict__ out_part,
                                             const float* __restrict__ den_part,
                                             const float* __restrict__ bias,
                                             float* __restrict__ out) {
    int idx4 = blockIdx.x * 128 + threadIdx.x;   // 65536 float4s
    int base = idx4 * 4;
    int i = base >> 6;
    int t = base & 63;
    float4 sacc = {0.f, 0.f, 0.f, 0.f};
    float dacc = 0.f;
#pragma unroll
    for (int p = 0; p < NPART; ++p) {
        float4 v = ((const float4*)(out_part + (size_t)p * N_NODES * F_OUT))[idx4];
        sacc.x += v.x; sacc.y += v.y; sacc.z += v.z; sacc.w += v.w;
        dacc += den_part[p * N_NODES + i];
    }
    float4 bv = *(const float4*)(bias + t);
    float4 o;
    o.x = fmaxf(sacc.x / dacc, 0.f) + bv.x;
    o.y = fmaxf(sacc.y / dacc, 0.f) + bv.y;
    o.z = fmaxf(sacc.z / dacc, 0.f) + bv.z;
    o.w = fmaxf(sacc.w / dacc, 0.f) + bv.w;
    ((float4*)out)[idx4] = o;
}

extern "C" void kernel_launch(void* const* d_in, const int* in_sizes, int n_in,
                              void* d_out, int out_size, void* d_ws, size_t ws_size,
                              hipStream_t stream) {
    const float* x    = (const float*)d_in[0];
    const int*   adj  = (const int*)d_in[1];
    const float* W    = (const float*)d_in[2];
    const float* a    = (const float*)d_in[3];
    const float* bias = (const float*)d_in[4];
    float* out = (float*)d_out;

    char* ws = (char*)d_ws;
    float*    h        = (float*)ws;                             // 1 MB
    _Float16* hT       = (_Float16*)(ws + 1024 * 1024);          // 512 KB
    float*    e1       = (float*)(ws + 1536 * 1024);             // 16 KB
    uint32_t* bm       = (uint32_t*)(ws + 2176 * 1024);          // 2 MB bitmap
    float*    out_part = (float*)(ws + 4224 * 1024);             // 16 MB (NPART=16, fp32)
    float*    den_part = (float*)(ws + (4224 + 16384) * 1024);   // 256 KB

    k_pre  <<<1280, 512, 0, stream>>>(x, adj, W, a, bm, h, hT, e1);
    k_main3<<<1024, 256, 0, stream>>>(bm, h, e1, a, hT, out_part, den_part);
    k_out  <<<512, 128, 0, stream>>>(out_part, den_part, bias, out);
}